// Round 9
// baseline (175.252 us; speedup 1.0000x reference)
//
#include <hip/hip_runtime.h>
#include <stdint.h>

#define B_ 32
#define E_ 256
#define L_ 2048
#define D_ 256

#define KS 4                  // k-split factor
#define KCHUNK (L_ / KS)      // 512
#define BK 32                 // k per step
#define NKT (KCHUNK / BK)     // 16 steps

#define SLAB_FLOATS ((size_t)B_ * E_ * D_)          // 8 MB
#define WS_NEED     (KS * SLAB_FLOATS * 4)          // 32 MB

typedef __attribute__((ext_vector_type(4))) float  f32x4;
typedef __attribute__((ext_vector_type(8))) short  s16x8;

// fp32 -> (hi, lo) bf16 pair. hi = truncated bf16(x); lo = bf16(x - hi).
__device__ __forceinline__ void cvt_hilo1(float x, short &h, short &l) {
    unsigned u = __builtin_bit_cast(unsigned, x);
    h = (short)(u >> 16);
    float hf = __builtin_bit_cast(float, u & 0xFFFF0000u);
    unsigned r = __builtin_bit_cast(unsigned, x - hf);
    l = (short)(r >> 16);
}

__global__ void zero_out_kernel(f32x4* __restrict__ out) {
    out[(size_t)blockIdx.x * 256 + threadIdx.x] = f32x4{0.f, 0.f, 0.f, 0.f};
}

// ---- reduce: out[i] = (ws0[i]+ws1[i]+ws2[i]+ws3[i]) / lens[row] ----
__global__ __launch_bounds__(256)
void reduce_kernel(const f32x4* __restrict__ ws, const float* __restrict__ lens,
                   f32x4* __restrict__ out) {
    const size_t i = (size_t)blockIdx.x * 256 + threadIdx.x;   // f32x4 index
    const float lv = lens[i >> 6];                              // 64 f32x4 per (b,e) row
    f32x4 s0 = ws[i];
    f32x4 s1 = ws[i +     (SLAB_FLOATS / 4)];
    f32x4 s2 = ws[i + 2 * (SLAB_FLOATS / 4)];
    f32x4 s3 = ws[i + 3 * (SLAB_FLOATS / 4)];
    f32x4 r;
    #pragma unroll
    for (int c = 0; c < 4; ++c) r[c] = (s0[c] + s1[c] + s2[c] + s3[c]) / lv;
    out[i] = r;
}

// direct global->LDS DMA, 16B per lane, dest = wave-uniform base + lane*16
__device__ __forceinline__ void gload16(const float* g, float* l) {
    __builtin_amdgcn_global_load_lds(
        (const __attribute__((address_space(1))) void*)g,
        (__attribute__((address_space(3))) void*)l, 16, 0, 0);
}

// ---- A (emap): DMA this wave's PRIVATE 64e x 32k fp32 tile, 8 instrs ----
// LDS content[r][q16] = global[r][q16 ^ (r&7)]  (16B quads, R5-verified layout)
#define ISSUE_A(BUF, K0)                                                       \
    {                                                                          \
        _Pragma("unroll")                                                      \
        for (int i = 0; i < 8; ++i) {                                          \
            const int r_ = i * 8 + a_r8;                                       \
            const int q_ = a_q ^ (r_ & 7);                                     \
            gload16(AgW + (size_t)r_ * L_ + (K0) + q_ * 4, (BUF) + i * 256);   \
        }                                                                      \
    }

// ---- B (doc): direct fragment gather into regs, 32 dword instrs ----
// instr (ni,j): 4 kg-rows x 64B contiguous = 4 fully-used cachelines
#define LOADB(PB, K0)                                                          \
    {                                                                          \
        _Pragma("unroll")                                                      \
        for (int ni = 0; ni < 4; ++ni)                                         \
            _Pragma("unroll")                                                  \
            for (int j = 0; j < 8; ++j)                                        \
                PB[ni][j] = Sg[(size_t)((K0) + kg * 8 + j) * D_ + ni * 16 + ml]; \
    }

// ---- one fully wave-local step: NO s_barrier anywhere in the kernel ----
#define STEP(K, BUFC, BUFN)                                                    \
    {                                                                          \
        if ((K) + 1 < NKT) ISSUE_A(BUFN, ((K) + 1) * BK)                       \
        /* drains A(K) DMA + B(K) regs; leaves A(K+1)'s 8 in flight */         \
        asm volatile("s_waitcnt vmcnt(8)" ::: "memory");                       \
        s16x8 bh[4], bl[4];                                                    \
        _Pragma("unroll")                                                      \
        for (int ni = 0; ni < 4; ++ni)                                         \
            _Pragma("unroll")                                                  \
            for (int j = 0; j < 8; ++j) {                                      \
                short hh, ll; cvt_hilo1(pbv[ni][j], hh, ll);                   \
                bh[ni][j] = hh; bl[ni][j] = ll;                                \
            }                                                                  \
        if ((K) + 1 < NKT) LOADB(pbv, ((K) + 1) * BK)                          \
        __builtin_amdgcn_s_setprio(1);                                         \
        _Pragma("unroll")                                                      \
        for (int mi = 0; mi < 4; ++mi) {                                       \
            const int row_ = mi * 16 + ml;                                     \
            const f32x4 alo = *(const f32x4*)((BUFC) + row_ * 32 + a_c1);      \
            const f32x4 ahi = *(const f32x4*)((BUFC) + row_ * 32 + a_c2);      \
            s16x8 ah, al;                                                      \
            _Pragma("unroll")                                                  \
            for (int q = 0; q < 4; ++q) { short hh, ll; cvt_hilo1(alo[q], hh, ll); ah[q] = hh; al[q] = ll; } \
            _Pragma("unroll")                                                  \
            for (int q = 0; q < 4; ++q) { short hh, ll; cvt_hilo1(ahi[q], hh, ll); ah[4 + q] = hh; al[4 + q] = ll; } \
            _Pragma("unroll")                                                  \
            for (int ni = 0; ni < 4; ++ni) {                                   \
                acc[mi][ni] = __builtin_amdgcn_mfma_f32_16x16x32_bf16(ah, bh[ni], acc[mi][ni], 0, 0, 0); \
                acc[mi][ni] = __builtin_amdgcn_mfma_f32_16x16x32_bf16(ah, bl[ni], acc[mi][ni], 0, 0, 0); \
                acc[mi][ni] = __builtin_amdgcn_mfma_f32_16x16x32_bf16(al, bh[ni], acc[mi][ni], 0, 0, 0); \
            }                                                                  \
        }                                                                      \
        __builtin_amdgcn_s_setprio(0);                                         \
    }

template <int WS>
__global__ __launch_bounds__(256, 2)
void mean_pool_kernel(const float* __restrict__ doc,
                      const float* __restrict__ emap,
                      const float* __restrict__ lens,
                      float* __restrict__ out,
                      float* __restrict__ wsp) {
    // 4 waves x 2 dbuf x (64 rows x 32 k) fp32 = 64 KB, all wave-PRIVATE.
    __shared__ __align__(16) float Apl[4][2][2048];

    const int t   = threadIdx.x;
    const int blk = blockIdx.x;
    const int ks  = blk & 3;
    const int dB  = (blk >> 2) & 1;
    const int eB  = (blk >> 3) & 1;
    const int b   = blk >> 4;

    // wave coords: 4 waves as 2(e) x 2(d), wave tile 64e x 64d
    const int lane = t & 63;
    const int w    = t >> 6;
    const int eo   = (w & 1) * 64;
    const int dq   = (w >> 1) * 64;
    const int ml   = lane & 15;
    const int kg   = lane >> 4;

    // this wave's private global bases
    const float* AgW = emap + ((size_t)(b * E_ + eB * 128 + eo)) * L_ + ks * KCHUNK;
    const float* Sg  = doc  + (size_t)b * L_ * D_ + (size_t)ks * KCHUNK * D_ + dB * 128 + dq;

    // A DMA lane coords (8 rows x 128B per instr, source pre-swizzled)
    const int a_r8 = lane >> 3;
    const int a_q  = lane & 7;
    // A frag-read float offsets within a 32-float row (R5-verified swizzle)
    const int a_c1 = (((2 * kg)    ) ^ (ml & 7)) * 4;
    const int a_c2 = (((2 * kg) | 1) ^ (ml & 7)) * 4;

    float* const Ab0 = &Apl[w][0][0];
    float* const Ab1 = &Apl[w][1][0];

    f32x4 acc[4][4] = {};
    float pbv[4][8];            // B fragment regs (fully static-indexed)

    // ---- prologue: tile 0 in flight ----
    ISSUE_A(Ab0, 0)
    LOADB(pbv, 0)

    // ---- main loop: 2x expansion, fully static buffer indices ----
    for (int kt = 0; kt < NKT; kt += 2) {
        STEP(kt,     Ab0, Ab1)
        STEP(kt + 1, Ab1, Ab0)
    }

    if (WS) {
        // ---- plain coalesced stores of partials into ws[ks][b][e][d] ----
        float* wsb = wsp + (size_t)ks * SLAB_FLOATS
                         + ((size_t)(b * E_ + eB * 128 + eo)) * D_ + dB * 128 + dq;
        #pragma unroll
        for (int mi = 0; mi < 4; ++mi) {
            #pragma unroll
            for (int rr = 0; rr < 4; ++rr) {
                const int er = mi * 16 + kg * 4 + rr;
                #pragma unroll
                for (int ni = 0; ni < 4; ++ni)
                    wsb[(size_t)er * D_ + ni * 16 + ml] = acc[mi][ni][rr];
            }
        }
    } else {
        // ---- fallback: atomic accumulation ----
        #pragma unroll
        for (int mi = 0; mi < 4; ++mi) {
            #pragma unroll
            for (int rr = 0; rr < 4; ++rr) {
                const int er = mi * 16 + kg * 4 + rr;
                const float lv = lens[b * E_ + eB * 128 + eo + er];
                #pragma unroll
                for (int ni = 0; ni < 4; ++ni)
                    atomicAdd(&out[((size_t)(b * E_ + eB * 128 + eo + er)) * D_
                                   + dB * 128 + dq + ni * 16 + ml],
                              acc[mi][ni][rr] / lv);
            }
        }
    }
}

extern "C" void kernel_launch(void* const* d_in, const int* in_sizes, int n_in,
                              void* d_out, int out_size, void* d_ws, size_t ws_size,
                              hipStream_t stream) {
    const float* doc  = (const float*)d_in[0];   // [32][2048][256]
    const float* emap = (const float*)d_in[1];   // [32][256][2048]
    const float* lens = (const float*)d_in[2];   // [32][256]
    float* out = (float*)d_out;                  // [32][256][256]
    float* ws  = (float*)d_ws;

    dim3 grid(B_ * KS * (E_ / 128) * (D_ / 128));  // 512 workgroups, 2/CU, all resident
    dim3 block(256);

    if (ws_size >= (size_t)WS_NEED) {
        // no atomics: partials -> workspace slabs, then streaming reduce
        hipLaunchKernelGGL((mean_pool_kernel<1>), grid, block, 0, stream,
                           doc, emap, lens, out, ws);
        hipLaunchKernelGGL(reduce_kernel,
                           dim3((unsigned)(SLAB_FLOATS / 4 / 256)), dim3(256), 0, stream,
                           (const f32x4*)ws, lens, (f32x4*)out);
    } else {
        // fallback: proven atomic path
        zero_out_kernel<<<dim3(out_size / (4 * 256)), dim3(256), 0, stream>>>((f32x4*)out);
        hipLaunchKernelGGL((mean_pool_kernel<0>), grid, block, 0, stream,
                           doc, emap, lens, out, ws);
    }
}

// Round 10
// 171.788 us; speedup vs baseline: 1.0202x; 1.0202x over previous
//
#include <hip/hip_runtime.h>
#include <stdint.h>

#define B_ 32
#define E_ 256
#define L_ 2048
#define D_ 256

#define BE 64
#define BD 64
#define BK 64
#define KS 2                  // k-split factor
#define KCHUNK (L_ / KS)      // 1024
#define NKT (KCHUNK / BK)     // 16 k-tiles per block

#define SLAB_FLOATS ((size_t)B_ * E_ * D_)          // 2,097,152 floats = 8 MB
#define WS_NEED     (KS * SLAB_FLOATS * 4)          // 16 MB

typedef __attribute__((ext_vector_type(2))) float    f32x2;
typedef __attribute__((ext_vector_type(4))) float    f32x4;
typedef __attribute__((ext_vector_type(8))) short    s16x8;
typedef __attribute__((ext_vector_type(2))) unsigned u32x2;
typedef __attribute__((ext_vector_type(4))) unsigned u32x4;

// ---- bf16 hi/lo packing via v_perm_b32: 3 VALU/element vs ~10 scalar ----
// hi dword = [bf16(x0) | bf16(x1)<<16]  (truncation, bit-identical to cvt_hilo1)
__device__ __forceinline__ unsigned pack_hi_pair(float x0, float x1) {
    return __builtin_amdgcn_perm(__builtin_bit_cast(unsigned, x1),
                                 __builtin_bit_cast(unsigned, x0), 0x07060302u);
}
// lo dword = [bf16(x0-hi0) | bf16(x1-hi1)<<16]
__device__ __forceinline__ unsigned pack_lo_pair(float x0, float x1) {
    unsigned u0 = __builtin_bit_cast(unsigned, x0);
    unsigned u1 = __builtin_bit_cast(unsigned, x1);
    float l0 = x0 - __builtin_bit_cast(float, u0 & 0xFFFF0000u);
    float l1 = x1 - __builtin_bit_cast(float, u1 & 0xFFFF0000u);
    return __builtin_amdgcn_perm(__builtin_bit_cast(unsigned, l1),
                                 __builtin_bit_cast(unsigned, l0), 0x07060302u);
}

__global__ void zero_out_kernel(f32x4* __restrict__ out) {
    out[(size_t)blockIdx.x * 256 + threadIdx.x] = f32x4{0.f, 0.f, 0.f, 0.f};
}

// ---- reduce: out[i] = (ws0[i]+ws1[i]) / lens[row] ----
__global__ __launch_bounds__(256)
void reduce_kernel(const f32x4* __restrict__ ws, const float* __restrict__ lens,
                   f32x4* __restrict__ out) {
    const size_t i = (size_t)blockIdx.x * 256 + threadIdx.x;   // f32x4 index
    const float lv = lens[i >> 6];                              // 64 f32x4 per (b,e) row
    f32x4 s0 = ws[i];
    f32x4 s1 = ws[i + (SLAB_FLOATS / 4)];
    f32x4 r;
    #pragma unroll
    for (int c = 0; c < 4; ++c) r[c] = (s0[c] + s1[c]) / lv;
    out[i] = r;
}

// lgkm-only drain + raw barrier: LDS ops ordered, but the 12 prefetch global
// loads stay in flight across the barrier (no vmcnt(0) drain like __syncthreads).
// Correctness (single-buffered LDS): each wave's ds_reads are complete (lgkmcnt 0)
// before it enters the barrier; writes after the barrier can't pass it.
#define LGKM_BARRIER()                                                         \
    {                                                                          \
        asm volatile("s_waitcnt lgkmcnt(0)" ::: "memory");                     \
        __builtin_amdgcn_s_barrier();                                          \
        asm volatile("" ::: "memory");                                         \
    }

template <int WS>
__global__ __launch_bounds__(256, 5)
void mean_pool_kernel(const float* __restrict__ doc,
                      const float* __restrict__ emap,
                      const float* __restrict__ lens,
                      float* __restrict__ out,
                      float* __restrict__ wsp) {
    // R7/R8 measured-zero-conflict layout + swizzle keys, unchanged.
    __shared__ __align__(16) short As_hi[BE][BK];
    __shared__ __align__(16) short As_lo[BE][BK];
    __shared__ __align__(16) short Bs_hi[BD][BK];   // doc^T tile: [d][k]
    __shared__ __align__(16) short Bs_lo[BD][BK];

    const int t   = threadIdx.x;
    const int blk = blockIdx.x;
    const int ks  = blk & 1;
    const int d0  = ((blk >> 1) & 3) * BD;
    const int e0  = ((blk >> 3) & 3) * BE;
    const int b   = blk >> 5;

    const float* Ag = emap + ((size_t)b * E_ + e0) * L_ + ks * KCHUNK;
    const float* Sg = doc  + (size_t)b * L_ * D_ + (size_t)ks * KCHUNK * D_ + d0;

    // A staging coords: 16 lanes per e-row (k-contiguous float4), rows t>>4 + rr*16
    const int a_c4 = t & 15;
    const int a_r  = t >> 4;
    // B staging coords: micro-tile 8k x 2d per thread
    const int db = t & 31;     // d-pair index (0..31) -> d = db*2, db*2+1
    const int kb = t >> 5;     // k-octet (0..7)       -> k = kb*8

    // wave coords: 4 waves as 2(e) x 2(d), wave tile 32e x 32d
    const int lane = t & 63;
    const int w    = t >> 6;
    const int eo   = (w & 1) * 32;
    const int dq   = (w >> 1) * 32;
    const int ml   = lane & 15;
    const int kg   = lane >> 4;

    f32x4 acc[2][2] = {};
    f32x4 pa[4];
    f32x2 pb[8];

    // preload tile 0
    #pragma unroll
    for (int rr = 0; rr < 4; ++rr)
        pa[rr] = *(const f32x4*)(Ag + (size_t)(a_r + rr * 16) * L_ + a_c4 * 4);
    #pragma unroll
    for (int i = 0; i < 8; ++i)
        pb[i] = *(const f32x2*)(Sg + (size_t)(kb * 8 + i) * D_ + db * 2);

    for (int kt = 0; kt < NKT; ++kt) {
        // ---- convert & stage to LDS (v_perm packed pairs, same addresses) ----
        #pragma unroll
        for (int rr = 0; rr < 4; ++rr) {
            const int row = a_r + rr * 16;
            const int col = (((a_c4 >> 1) ^ (row & 7)) << 3) + (a_c4 & 1) * 4;
            u32x2 h, l;
            h[0] = pack_hi_pair(pa[rr][0], pa[rr][1]);
            h[1] = pack_hi_pair(pa[rr][2], pa[rr][3]);
            l[0] = pack_lo_pair(pa[rr][0], pa[rr][1]);
            l[1] = pack_lo_pair(pa[rr][2], pa[rr][3]);
            *(u32x2*)&As_hi[row][col] = h;
            *(u32x2*)&As_lo[row][col] = l;
        }
        #pragma unroll
        for (int dd = 0; dd < 2; ++dd) {
            const int row = db * 2 + dd;
            const int key = (db & 3) | (((db >> 2) & 1) << 2);   // == ((row>>1)&3)|(((row>>3)&1)<<2)
            const int col = (kb ^ key) << 3;
            u32x4 h, l;
            #pragma unroll
            for (int p = 0; p < 4; ++p) {
                h[p] = pack_hi_pair(pb[2 * p][dd], pb[2 * p + 1][dd]);
                l[p] = pack_lo_pair(pb[2 * p][dd], pb[2 * p + 1][dd]);
            }
            *(u32x4*)&Bs_hi[row][col] = h;
            *(u32x4*)&Bs_lo[row][col] = l;
        }

        // ---- issue next tile's globals BEFORE the barrier (max latency cover;
        //      loads stay in flight across the lgkm-only barrier) ----
        if (kt + 1 < NKT) {
            const int k0 = (kt + 1) * BK;
            #pragma unroll
            for (int rr = 0; rr < 4; ++rr)
                pa[rr] = *(const f32x4*)(Ag + (size_t)(a_r + rr * 16) * L_ + k0 + a_c4 * 4);
            #pragma unroll
            for (int i = 0; i < 8; ++i)
                pb[i] = *(const f32x2*)(Sg + (size_t)(k0 + kb * 8 + i) * D_ + db * 2);
        }
        LGKM_BARRIER();

        // ---- MFMA: 3-pass hi/lo split (unchanged) ----
        #pragma unroll
        for (int kc = 0; kc < 2; ++kc) {
            const int gbase = kc * 4;
            s16x8 ah[2], al[2], bh[2], bl[2];
            #pragma unroll
            for (int mi = 0; mi < 2; ++mi) {
                const int row = eo + mi * 16 + ml;
                const int col = ((gbase + kg) ^ (row & 7)) << 3;
                ah[mi] = *(const s16x8*)&As_hi[row][col];
                al[mi] = *(const s16x8*)&As_lo[row][col];
            }
            #pragma unroll
            for (int ni = 0; ni < 2; ++ni) {
                const int row = dq + ni * 16 + ml;
                const int keyB = ((row >> 1) & 3) | (((row >> 3) & 1) << 2);
                const int col  = ((gbase + kg) ^ keyB) << 3;
                bh[ni] = *(const s16x8*)&Bs_hi[row][col];
                bl[ni] = *(const s16x8*)&Bs_lo[row][col];
            }
            #pragma unroll
            for (int mi = 0; mi < 2; ++mi)
                #pragma unroll
                for (int ni = 0; ni < 2; ++ni) {
                    acc[mi][ni] = __builtin_amdgcn_mfma_f32_16x16x32_bf16(ah[mi], bh[ni], acc[mi][ni], 0, 0, 0);
                    acc[mi][ni] = __builtin_amdgcn_mfma_f32_16x16x32_bf16(ah[mi], bl[ni], acc[mi][ni], 0, 0, 0);
                    acc[mi][ni] = __builtin_amdgcn_mfma_f32_16x16x32_bf16(al[mi], bh[ni], acc[mi][ni], 0, 0, 0);
                }
        }
        LGKM_BARRIER();
    }

    if (WS) {
        // ---- plain coalesced stores of partials into ws[ks][b][e][d] (R6-proven) ----
        float* wsb = wsp + (size_t)ks * SLAB_FLOATS;
        #pragma unroll
        for (int mi = 0; mi < 2; ++mi) {
            #pragma unroll
            for (int rr = 0; rr < 4; ++rr) {
                const int er = eo + mi * 16 + kg * 4 + rr;
                #pragma unroll
                for (int ni = 0; ni < 2; ++ni)
                    wsb[((size_t)(b * E_ + e0 + er)) * D_ + d0 + dq + ni * 16 + ml] =
                        acc[mi][ni][rr];
            }
        }
    } else {
        // ---- fallback: atomic accumulation ----
        __shared__ float lens_s[BE];
        if (t < BE) lens_s[t] = lens[b * E_ + e0 + t];
        __syncthreads();
        #pragma unroll
        for (int mi = 0; mi < 2; ++mi) {
            #pragma unroll
            for (int rr = 0; rr < 4; ++rr) {
                const int er = eo + mi * 16 + kg * 4 + rr;
                const float lv = lens_s[er];
                #pragma unroll
                for (int ni = 0; ni < 2; ++ni)
                    atomicAdd(&out[((size_t)(b * E_ + e0 + er)) * D_ + d0 + dq + ni * 16 + ml],
                              acc[mi][ni][rr] / lv);
            }
        }
    }
}

extern "C" void kernel_launch(void* const* d_in, const int* in_sizes, int n_in,
                              void* d_out, int out_size, void* d_ws, size_t ws_size,
                              hipStream_t stream) {
    const float* doc  = (const float*)d_in[0];   // [32][2048][256]
    const float* emap = (const float*)d_in[1];   // [32][256][2048]
    const float* lens = (const float*)d_in[2];   // [32][256]
    float* out = (float*)d_out;                  // [32][256][256]
    float* ws  = (float*)d_ws;

    dim3 grid(B_ * (E_ / BE) * (D_ / BD) * KS);  // 1024 workgroups, ~4 blocks/CU
    dim3 block(256);

    if (ws_size >= (size_t)WS_NEED) {
        // no atomics: partials -> workspace slabs, then streaming reduce
        hipLaunchKernelGGL((mean_pool_kernel<1>), grid, block, 0, stream,
                           doc, emap, lens, out, ws);
        hipLaunchKernelGGL(reduce_kernel,
                           dim3((unsigned)(SLAB_FLOATS / 4 / 256)), dim3(256), 0, stream,
                           (const f32x4*)ws, lens, (f32x4*)out);
    } else {
        // fallback: proven atomic path
        zero_out_kernel<<<dim3(out_size / (4 * 256)), dim3(256), 0, stream>>>((f32x4*)out);
        hipLaunchKernelGGL((mean_pool_kernel<0>), grid, block, 0, stream,
                           doc, emap, lens, out, ws);
    }
}